// Round 15
// baseline (169.505 us; speedup 1.0000x reference)
//
#include <hip/hip_runtime.h>
#include <hip/hip_bf16.h>
#include <math.h>

#define NB 65536
#define DIN 1024
#define NQ 64
#define DOUT 1024

typedef __attribute__((ext_vector_type(8))) short bf16x8;
typedef __attribute__((ext_vector_type(4))) float f32x4;
typedef unsigned short u16;

__device__ __forceinline__ u16 f2bf(float f) {
    union { float f; unsigned u; } v; v.f = f;
    return (u16)((v.u + 0x7fffu + ((v.u >> 16) & 1u)) >> 16);
}

// ---- kP: row-major bf16 weights + per-q constants (R13/R14 verbatim) --------
__global__ __launch_bounds__(256) void kP(const float* __restrict__ W_in,
                                          const float* __restrict__ W_out,
                                          const float* __restrict__ qp,
                                          u16* __restrict__ Wb,
                                          u16* __restrict__ Wob,
                                          float* __restrict__ cp0,
                                          float* __restrict__ cq) {
    int i = blockIdx.x * 256 + threadIdx.x;
    if (i < NQ * DIN)  Wb[i]  = f2bf(W_in[i]);
    if (i < DOUT * NQ) Wob[i] = f2bf(W_out[i]);
    if (i < NQ) {
        cp0[i] = cosf(qp[i * 3 + 0]);
        cq[i]  = sinf(qp[i * 3 + 1]) * cosf(qp[i * 3 + 2]);
    }
}

// ---- kA: GEMM1 + quantum epilogue, Wb LDS-resident (R14 verbatim) -----------
__global__ __launch_bounds__(512) void kA(const float* __restrict__ x,
                                          const u16* __restrict__ Wb,
                                          const float* __restrict__ b_in,
                                          const float* __restrict__ cp0,
                                          const float* __restrict__ cq,
                                          u16* __restrict__ state) {
    __shared__ u16 WbL[NQ * DIN];                 // 128 KB, [64 rows][128 units]

    const int tid = threadIdx.x;
    const int w = tid >> 6, l = tid & 63;
    const int r = l & 15, kg = l >> 4;
    const int row0 = blockIdx.x * 128 + w * 16;

    #pragma unroll
    for (int c = 0; c < 16; ++c) {
        int g   = c * 512 + tid;
        int row = g >> 7;
        int u   = g & 127;
        int us  = (u & 120) | ((u ^ row) & 7);
        *(bf16x8*)((char*)WbL + row * 2048 + us * 16) =
            *(const bf16x8*)((const char*)Wb + (size_t)g * 16);
    }
    __syncthreads();

    const float* xrow = x + (size_t)(row0 + r) * DIN + kg * 8;

    f32x4 acc[4] = {f32x4{0,0,0,0}, f32x4{0,0,0,0}, f32x4{0,0,0,0}, f32x4{0,0,0,0}};

    float4 xa = *(const float4*)(xrow);
    float4 xb = *(const float4*)(xrow + 4);
    for (int k0 = 0; k0 < DIN; k0 += 32) {
        float4 na, nb;
        if (k0 < DIN - 32) {
            na = *(const float4*)(xrow + k0 + 32);
            nb = *(const float4*)(xrow + k0 + 36);
        }
        union { bf16x8 v; unsigned u[4]; } a;
        asm("v_cvt_pk_bf16_f32 %0, %1, %2" : "=v"(a.u[0]) : "v"(xa.x), "v"(xa.y));
        asm("v_cvt_pk_bf16_f32 %0, %1, %2" : "=v"(a.u[1]) : "v"(xa.z), "v"(xa.w));
        asm("v_cvt_pk_bf16_f32 %0, %1, %2" : "=v"(a.u[2]) : "v"(xb.x), "v"(xb.y));
        asm("v_cvt_pk_bf16_f32 %0, %1, %2" : "=v"(a.u[3]) : "v"(xb.z), "v"(xb.w));
        #pragma unroll
        for (int n = 0; n < 4; ++n) {
            const int row = n * 16 + r;
            const int u   = (k0 >> 3) + kg;
            const int us  = (u & 120) | ((u ^ r) & 7);
            bf16x8 b = *(const bf16x8*)((const char*)WbL + row * 2048 + us * 16);
            acc[n] = __builtin_amdgcn_mfma_f32_16x16x32_bf16(a.v, b, acc[n], 0, 0, 0);
        }
        xa = na; xb = nb;
    }

    #pragma unroll
    for (int n = 0; n < 4; ++n) {
        const int q = n * 16 + r;
        const float bi = b_in[q], c0q = cp0[q], c1q = cq[q];
        #pragma unroll
        for (int i = 0; i < 4; ++i) {
            float av = acc[n][i] + bi;
            float e2 = __builtin_amdgcn_exp2f(av * 2.8853900817779268f);   // 2*log2e
            float th = 1.0f - 2.0f * __builtin_amdgcn_rcpf(e2 + 1.0f);     // tanh
            float sv = __builtin_amdgcn_cosf(th * 0.25f) * c0q + c1q;      // cos(th*pi/2)
            state[(size_t)(row0 + kg * 4 + i) * NQ + q] = f2bf(sv);
        }
    }
}

// ---- kB: GEMM2, Wob LDS-resident + LDS-transposed BURST stores --------------
// 512 blocks x 512 thr. Compute/swizzle/frag paths = R14 verbatim. New: output
// goes through per-wave LDS tile [16 rows][32 cols] (stride 33 f32), then 2
// dwordx4 store instrs per 32-col group: 8 rows x 128B CONTIGUOUS segments
// (vs R14's 4 rows x 64B scattered dwords). Bias folded at LDS-write.
__global__ __launch_bounds__(512) void kB(const u16* __restrict__ state,
                                          const u16* __restrict__ Wob,
                                          const float* __restrict__ b_out,
                                          float* __restrict__ out) {
    __shared__ u16   WobL[DOUT * NQ];             // 128 KB
    __shared__ float xp[8][528];                  // per-wave [16][33] f32, 16.5 KB
    __shared__ float boutL[DOUT];                 // 4 KB

    const int tid = threadIdx.x;
    const int w = tid >> 6, l = tid & 63;
    const int r = l & 15, kg = l >> 4;
    const int row0 = blockIdx.x * 128 + w * 16;

    #pragma unroll
    for (int c = 0; c < 16; ++c) {
        int g   = c * 512 + tid;
        int row = g >> 3;
        int us  = (g ^ row) & 7;
        *(bf16x8*)((char*)WobL + row * 128 + us * 16) =
            *(const bf16x8*)((const char*)Wob + (size_t)g * 16);
    }
    boutL[tid]       = b_out[tid];
    boutL[tid + 512] = b_out[tid + 512];
    __syncthreads();

    const u16* srow = state + (size_t)(row0 + r) * NQ + kg * 8;
    bf16x8 sa0 = *(const bf16x8*)(srow);          // k = kg*8 + j
    bf16x8 sa1 = *(const bf16x8*)(srow + 32);     // k = 32 + kg*8 + j

    float* xpw = xp[w];

    for (int g = 0; g < 32; ++g) {                // 32 groups of 32 cols
        #pragma unroll
        for (int t = 0; t < 2; ++t) {
            const int col = (g * 2 + t) * 16 + r;               // col&7 == r&7
            const int us0 = (kg     ^ r) & 7;
            const int us1 = ((4+kg) ^ r) & 7;
            bf16x8 b0 = *(const bf16x8*)((const char*)WobL + col * 128 + us0 * 16);
            bf16x8 b1 = *(const bf16x8*)((const char*)WobL + col * 128 + us1 * 16);
            f32x4 a2 = {0.0f, 0.0f, 0.0f, 0.0f};
            a2 = __builtin_amdgcn_mfma_f32_16x16x32_bf16(sa0, b0, a2, 0, 0, 0);
            a2 = __builtin_amdgcn_mfma_f32_16x16x32_bf16(sa1, b1, a2, 0, 0, 0);
            const float bo = boutL[col];
            // D: value i belongs to (row kg*4+i, col t*16+r) -> LDS transpose tile
            #pragma unroll
            for (int i = 0; i < 4; ++i)
                xpw[(kg * 4 + i) * 33 + t * 16 + r] = a2[i] + bo;
        }
        // drain: lane -> (row p*8+(l>>3), cols (l&7)*4..+4); 128B/row segments
        #pragma unroll
        for (int p = 0; p < 2; ++p) {
            const int rr = p * 8 + (l >> 3);
            const int cc = (l & 7) * 4;
            float4 v;
            v.x = xpw[rr * 33 + cc + 0];
            v.y = xpw[rr * 33 + cc + 1];
            v.z = xpw[rr * 33 + cc + 2];
            v.w = xpw[rr * 33 + cc + 3];
            *(float4*)(out + (size_t)(row0 + rr) * DOUT + g * 32 + cc) = v;
        }
    }
}

extern "C" void kernel_launch(void* const* d_in, const int* in_sizes, int n_in,
                              void* d_out, int out_size, void* d_ws, size_t ws_size,
                              hipStream_t stream) {
    const float* x    = (const float*)d_in[0];
    const float* W_in = (const float*)d_in[1];
    const float* b_in = (const float*)d_in[2];
    const float* qp   = (const float*)d_in[3];
    const float* W_out= (const float*)d_in[4];
    const float* b_out= (const float*)d_in[5];
    float* out = (float*)d_out;

    char* ws = (char*)d_ws;
    u16*   Wb    = (u16*)(ws);               // 128 KB row-major bf16 W_in
    u16*   Wob   = (u16*)(ws + 131072);      // 128 KB row-major bf16 W_out
    float* cp0   = (float*)(ws + 262144);    // 256 B
    float* cq    = (float*)(ws + 262400);    // 256 B
    u16*   state = (u16*)(ws + 1048576);     // 8 MB row-major state

    kP<<<(NQ * DIN + 255) / 256, 256, 0, stream>>>(W_in, W_out, qp, Wb, Wob, cp0, cq);
    kA<<<NB / 128, 512, 0, stream>>>(x, Wb, b_in, cp0, cq, state);
    kB<<<NB / 128, 512, 0, stream>>>(state, Wob, b_out, out);
}